// Round 24
// baseline (358.978 us; speedup 1.0000x reference)
//
#include <hip/hip_runtime.h>
#include <math.h>

typedef _Float16 f16x8 __attribute__((ext_vector_type(8)));
typedef float f32x4 __attribute__((ext_vector_type(4)));
typedef float f32x16 __attribute__((ext_vector_type(16)));
typedef unsigned short us8 __attribute__((ext_vector_type(8)));
typedef unsigned short us4 __attribute__((ext_vector_type(4)));

#define PI_F 3.14159265358979323846f

__device__ __forceinline__ unsigned short f2h(float f){
  _Float16 hi = (_Float16)f;
  return __builtin_bit_cast(unsigned short, hi);
}

__device__ __forceinline__ float fast_gelu(float v){
  float u2 = v * v;
  float z  = v * fmaf(u2, 0.03567740814f, 0.7978845608f);
  float e  = __builtin_amdgcn_exp2f(z * 2.885390082f);   // 2*log2(e)
  float r  = __builtin_amdgcn_rcpf(e + 1.0f);
  return v - v * r;
}

__device__ __forceinline__ float fast_tanh(float v){
  float e = __builtin_amdgcn_exp2f(v * 2.885390082f);
  float r = __builtin_amdgcn_rcpf(e + 1.0f);
  return 1.0f - 2.0f * r;
}

// LDS tile addressing in ushort units, XOR swizzle for bank balance
#define ACOL(rr,cc) (((rr) << 8) + ((cc) ^ ((((rr) & 15)) << 3)))

#define LDW(ptr) __builtin_bit_cast(f16x8, *reinterpret_cast<const us8*>(ptr))

// ---------------- pyramid (jax.image.resize bilinear, antialias=True) -------
__global__ void pyr_kernel(const float* __restrict__ fg, float* __restrict__ out,
                           int Ho, int Wo, float inv_scale){
  int idx = blockIdx.x * blockDim.x + threadIdx.x;
  int total = 8 * Ho * Wo * 64;
  if (idx >= total) return;
  int c  = idx & 63;
  int xy = idx >> 6;
  int x  = xy % Wo;
  int y  = (xy / Wo) % Ho;
  int b  = xy / (Wo * Ho);
  float cyc = inv_scale * (y + 0.5f) - 0.5f;
  float cxc = inv_scale * (x + 0.5f) - 0.5f;
  int iy0 = (int)ceilf(cyc - inv_scale); if (iy0 < 0) iy0 = 0;
  int iy1 = (int)floorf(cyc + inv_scale); if (iy1 > 63) iy1 = 63;
  int ix0 = (int)ceilf(cxc - inv_scale); if (ix0 < 0) ix0 = 0;
  int ix1 = (int)floorf(cxc + inv_scale); if (ix1 > 63) ix1 = 63;
  float rinv = 1.0f / inv_scale;
  float wxs = 0.0f;
  for (int ix = ix0; ix <= ix1; ++ix){
    float w = 1.0f - fabsf(ix - cxc) * rinv;
    if (w > 0.0f) wxs += w;
  }
  float wys = 0.0f, acc = 0.0f;
  for (int iy = iy0; iy <= iy1; ++iy){
    float wy = 1.0f - fabsf(iy - cyc) * rinv;
    if (wy <= 0.0f) continue;
    wys += wy;
    const float* rowp = fg + (((b * 64) + iy) * 64) * 64 + c;
    for (int ix = ix0; ix <= ix1; ++ix){
      float wx = 1.0f - fabsf(ix - cxc) * rinv;
      if (wx <= 0.0f) continue;
      acc += wy * wx * rowp[ix * 64];
    }
  }
  out[idx] = acc / (wys * wxs);
}

// ------------- posenc table: PE[n][48] f16 (shared across images) -----------
__global__ void pe_kernel(const float* __restrict__ coords,
                          unsigned short* __restrict__ peh){
  int idx = blockIdx.x * 256 + threadIdx.x;   // < 196608
  if (idx >= 16384 * 12) return;
  int n = idx / 12, slot = idx % 12;
  const float cy = coords[2 * n], cx = coords[2 * n + 1];
  if (slot == 0){
    peh[n * 48 + 0] = f2h(cy);
    peh[n * 48 + 1] = f2h(cx);
  } else if (slot <= 10){
    int i = slot - 1;
    float f = PI_F * (float)(1 << i);
    float sy, cyv, sx, cxv;
    sincosf(cy * f, &sy, &cyv);
    sincosf(cx * f, &sx, &cxv);
    peh[n * 48 + 2 + 4 * i] = f2h(sy);
    peh[n * 48 + 3 + 4 * i] = f2h(sx);
    peh[n * 48 + 4 + 4 * i] = f2h(cyv);
    peh[n * 48 + 5 + 4 * i] = f2h(cxv);
  } else {
#pragma unroll
    for (int j = 42; j < 48; ++j) peh[n * 48 + j] = 0;
  }
}

// ------------- weight prep: pre-tiled per-lane 32x32x16 MFMA fragments ------
// WT[l][cfg][ks][lane][e]: col = cfg*32 + (lane&31), k = ks*16 + (lane>>5)*8 + e
// layer0 k-remap: k<42 -> W0 row k; 42..47 pad; 48..239 -> row k-6; 240..255 pad
__global__ void prep_wt(const float* __restrict__ W0, const float* __restrict__ W1,
                        const float* __restrict__ W2, const float* __restrict__ W3,
                        unsigned short* __restrict__ WTh){
  int idx = blockIdx.x * 256 + threadIdx.x;      // < 262144
  int l    = idx >> 16;
  int rem  = idx & 65535;
  int cfg  = rem >> 13;          // 0..7
  int ks   = (rem >> 9) & 15;    // 0..15
  int lane = (rem >> 3) & 63;
  int e    = idx & 7;
  int col  = cfg * 32 + (lane & 31);
  int k    = ks * 16 + (lane >> 5) * 8 + e;
  float v;
  if (l == 0){
    int row; bool valid;
    if (k < 42)                 { row = k;     valid = true; }
    else if (k >= 48 && k < 240){ row = k - 6; valid = true; }
    else                        { row = 0;     valid = false; }
    v = valid ? W0[row * 256 + col] : 0.0f;
  } else {
    const float* W = (l == 1) ? W1 : ((l == 2) ? W2 : W3);
    v = W[k * 256 + col];
  }
  WTh[idx] = f2h(v);
}

// ------------- FiLM params + Wout tiled fragments (16x16 head) --------------
__global__ void prep_misc(const float* __restrict__ cv, const float* __restrict__ Wc,
                          const float* __restrict__ bc, const float* __restrict__ Wout,
                          float* __restrict__ gamma, float* __restrict__ beta,
                          unsigned short* __restrict__ WoT){
  int idx = blockIdx.x * 256 + threadIdx.x;      // < 8192
  if (idx < 4096){
    int b = idx >> 9, j = idx & 511;
    float a = bc[j];
    for (int c = 0; c < 64; ++c) a += cv[b * 64 + c] * Wc[c * 512 + j];
    if (j < 256) gamma[b * 256 + j] = a + 1.0f;
    else         beta[b * 256 + (j - 256)] = a;
  } else {
    int j = idx - 4096;                // WoT[ks][lane][e]
    int ks = j >> 9, lane = (j >> 3) & 63, e = j & 7;
    int col = lane & 15;
    int k = ks * 32 + (lane >> 4) * 8 + e;
    float v = (col < 3) ? Wout[k * 3 + col] : 0.0f;
    WoT[j] = f2h(v);
  }
}

// ------------------------------- main ---------------------------------------
// R23 structure (wave-private barrier-free MLP, two column passes per layer)
// with the f32x16 ACCUMULATOR ARRAY replaced by FOUR NAMED f32x16 registers
// (acc0..acc3). Diagnosis: R19-R23 all spilled ~380MB/dispatch with VGPR
// pinned at 128 — the only construct separating them from the clean R13-R18
// kernels is an ARRAY of f32x16 (rule #20: arrays of wide ext_vectors go to
// scratch; named variables with compile-time access allocate cleanly — R18's
// f16x8 arrays were fine, so Bc[4]/st[8] stay).
__global__ __launch_bounds__(512, 1)
void dec_main(const float* __restrict__ fg, const float* __restrict__ coords,
              const float* __restrict__ p1, const float* __restrict__ p2,
              const unsigned short* __restrict__ WTh,
              const unsigned short* __restrict__ WoT,
              const unsigned short* __restrict__ peh,
              const float* __restrict__ gamma, const float* __restrict__ beta,
              const float* __restrict__ b0, const float* __restrict__ b1,
              const float* __restrict__ b2, const float* __restrict__ b3,
              const float* __restrict__ bout, float* __restrict__ out){
  __shared__ __align__(16) unsigned short T0[256 * 256];  // 128 KB activation tile
  __shared__ __align__(16) float Pgs[256];                // gamma
  __shared__ __align__(16) float C2s[4][256];             // bs*gm + bt per layer

  const int t  = threadIdx.x;
  const int bi = blockIdx.x >> 6;           // image 0..7
  const int n0 = (blockIdx.x & 63) * 256;   // first coord row of this block

  const int lane = t & 63;
  const int wv   = t >> 6;         // 0..7
  const int l15  = lane & 15;      // head (16x16) lane decode
  const int lg   = lane >> 4;
  const int l31  = lane & 31;      // 32x32 lane decode
  const int lhi  = lane >> 5;      // 0/1
  const int arow = wv * 32 + l31;  // this lane's activation row (0..255)

  // B ring: 4 slots (one per col group in the current pass); init = L0/passA/ks0
  f16x8 Bc[4];
#pragma unroll
  for (int c = 0; c < 4; ++c)
    Bc[c] = LDW(WTh + c * 8192 + lane * 8);

  // ---------------- phase 0: params + features into T0 (256 rows) ----------
  if (t < 256){
    const float gm = gamma[bi * 256 + t];
    const float bt = beta[bi * 256 + t];
    Pgs[t] = gm;
    C2s[0][t] = fmaf(b0[t], gm, bt);
    C2s[1][t] = fmaf(b1[t], gm, bt);
    C2s[2][t] = fmaf(b2[t], gm, bt);
    C2s[3][t] = fmaf(b3[t], gm, bt);
  }

#pragma unroll
  for (int pass = 0; pass < 2; ++pass){
    const int r = pass * 128 + (t >> 2), q = t & 3;   // 4 threads/row
    const int n = n0 + r;
    const float cy = coords[2 * n], cx = coords[2 * n + 1];

    if (q == 0){
      if (peh){
        const unsigned short* ph = peh + (size_t)n * 48;
#pragma unroll
        for (int u = 0; u < 6; ++u){
          us8 vh = *reinterpret_cast<const us8*>(ph + u * 8);
          *reinterpret_cast<us8*>(&T0[ACOL(r, u * 8)]) = vh;
        }
      } else {
        float e[48];
        e[0] = cy; e[1] = cx;
#pragma unroll
        for (int i = 0; i < 10; ++i){
          float f = PI_F * (float)(1 << i);
          float sy, cyv, sx, cxv;
          sincosf(cy * f, &sy, &cyv);
          sincosf(cx * f, &sx, &cxv);
          e[2 + 4 * i] = sy;
          e[3 + 4 * i] = sx;
          e[4 + 4 * i] = cyv;
          e[5 + 4 * i] = cxv;
        }
#pragma unroll
        for (int j = 42; j < 48; ++j) e[j] = 0.0f;
#pragma unroll
        for (int u = 0; u < 6; ++u){
          us8 vh;
#pragma unroll
          for (int j = 0; j < 8; ++j) vh[j] = f2h(e[8 * u + j]);
          *reinterpret_cast<us8*>(&T0[ACOL(r, u * 8)]) = vh;
        }
      }
    }
    if (q == 1){   // zero pad cols 240..255
      us8 z = {0,0,0,0,0,0,0,0};
      *reinterpret_cast<us8*>(&T0[ACOL(r, 240)]) = z;
      *reinterpret_cast<us8*>(&T0[ACOL(r, 248)]) = z;
    }

    // bilinear sample 16 channels per thread from each pyramid level
#pragma unroll
    for (int L = 0; L < 3; ++L){
      const int HL = 64 >> L;
      const float* g = (L == 0) ? fg : ((L == 1) ? p1 : p2);
      float yy = (cy + 1.0f) * 0.5f * (HL - 1);
      float xx = (cx + 1.0f) * 0.5f * (HL - 1);
      float y0f = floorf(yy), x0f = floorf(xx);
      float wy = yy - y0f, wx = xx - x0f;
      int y0 = (int)y0f, x0 = (int)x0f;
      y0 = min(max(y0, 0), HL - 1); x0 = min(max(x0, 0), HL - 1);
      int y1 = min(y0 + 1, HL - 1), x1 = min(x0 + 1, HL - 1);
      const int c0 = q * 16;
      const float* g00 = g + (((bi * HL + y0) * HL) + x0) * 64 + c0;
      const float* g01 = g + (((bi * HL + y0) * HL) + x1) * 64 + c0;
      const float* g10 = g + (((bi * HL + y1) * HL) + x0) * 64 + c0;
      const float* g11 = g + (((bi * HL + y1) * HL) + x1) * 64 + c0;
      float w00 = (1 - wy) * (1 - wx), w01 = (1 - wy) * wx;
      float w10 = wy * (1 - wx),       w11 = wy * wx;
      float o[16];
#pragma unroll
      for (int u = 0; u < 4; ++u){
        float4 v0 = *reinterpret_cast<const float4*>(g00 + 4 * u);
        float4 v1 = *reinterpret_cast<const float4*>(g01 + 4 * u);
        float4 v2 = *reinterpret_cast<const float4*>(g10 + 4 * u);
        float4 v3 = *reinterpret_cast<const float4*>(g11 + 4 * u);
        o[4*u+0] = w00*v0.x + w01*v1.x + w10*v2.x + w11*v3.x;
        o[4*u+1] = w00*v0.y + w01*v1.y + w10*v2.y + w11*v3.y;
        o[4*u+2] = w00*v0.z + w01*v1.z + w10*v2.z + w11*v3.z;
        o[4*u+3] = w00*v0.w + w01*v1.w + w10*v2.w + w11*v3.w;
      }
      us8 h0, h1;
#pragma unroll
      for (int j = 0; j < 8; ++j){
        h0[j] = f2h(o[j]);
        h1[j] = f2h(o[8 + j]);
      }
      const int colb = 48 + 64 * L + 16 * q;
      *reinterpret_cast<us8*>(&T0[ACOL(r, colb)])     = h0;
      *reinterpret_cast<us8*>(&T0[ACOL(r, colb + 8)]) = h1;
    }
  }
  __syncthreads();   // the ONLY barrier: phase-0 row mapping is cross-wave

  // ---------------- 4 FiLM-gelu MLP layers, barrier-free, 2 passes ---------
  // NAMED f32x16 accumulators (rule #20: no arrays of wide ext_vectors)
  f32x16 acc0, acc1, acc2, acc3;
  f16x8 st[8];       // pass-A stash (cols 0..127); f16x8 arrays proven clean (R18)

#define ZERO16(A) do { _Pragma("unroll") for (int j = 0; j < 16; ++j) (A)[j] = 0.0f; } while(0)

  // one K-step for column group C (compile-time), pass A
#define STEP_A(C, ACC) do { \
    f16x8 b_ = Bc[C]; \
    if (ks < 15) Bc[C] = LDW(Wl + (C) * 8192 + (ks + 1) * 512 + lane * 8); \
    else         Bc[C] = LDW(Wl + ((C) + 4) * 8192 + lane * 8); \
    ACC = __builtin_amdgcn_mfma_f32_32x32x16_f16(b_, ah, ACC, 0, 0, 0); \
  } while(0)

  // one K-step for column group C+4 (compile-time), pass B
#define STEP_B(C, ACC) do { \
    f16x8 b_ = Bc[C]; \
    if (ks < 15) Bc[C] = LDW(Wl + ((C) + 4) * 8192 + (ks + 1) * 512 + lane * 8); \
    else if (l < 3) Bc[C] = LDW(Wl + 65536 + (C) * 8192 + lane * 8); \
    ACC = __builtin_amdgcn_mfma_f32_32x32x16_f16(b_, ah, ACC, 0, 0, 0); \
  } while(0)

  // stash pass-A FiLM+gelu results for col group C into st[2C], st[2C+1]
#define STASH(C, ACC) do { \
    _Pragma("unroll") \
    for (int gp = 0; gp < 2; ++gp){ \
      const int cb2 = (C) * 32 + 16 * gp + 4 * lhi; \
      const float4 gmA = *reinterpret_cast<const float4*>(&Pgs[cb2]); \
      const float4 c2A = *reinterpret_cast<const float4*>(&C2s[l][cb2]); \
      const float4 gmB = *reinterpret_cast<const float4*>(&Pgs[cb2 + 8]); \
      const float4 c2B = *reinterpret_cast<const float4*>(&C2s[l][cb2 + 8]); \
      us8 hv; \
      hv[0] = f2h(fast_gelu(fmaf((ACC)[8*gp+0], gmA.x, c2A.x))); \
      hv[1] = f2h(fast_gelu(fmaf((ACC)[8*gp+1], gmA.y, c2A.y))); \
      hv[2] = f2h(fast_gelu(fmaf((ACC)[8*gp+2], gmA.z, c2A.z))); \
      hv[3] = f2h(fast_gelu(fmaf((ACC)[8*gp+3], gmA.w, c2A.w))); \
      hv[4] = f2h(fast_gelu(fmaf((ACC)[8*gp+4], gmB.x, c2B.x))); \
      hv[5] = f2h(fast_gelu(fmaf((ACC)[8*gp+5], gmB.y, c2B.y))); \
      hv[6] = f2h(fast_gelu(fmaf((ACC)[8*gp+6], gmB.z, c2B.z))); \
      hv[7] = f2h(fast_gelu(fmaf((ACC)[8*gp+7], gmB.w, c2B.w))); \
      st[(C) * 2 + gp] = __builtin_bit_cast(f16x8, hv); \
    } } while(0)

  // pass-B epilogue: FiLM+gelu + vectorized write for col group C+4
#define WRITE_B(C, ACC) do { \
    _Pragma("unroll") \
    for (int gp = 0; gp < 2; ++gp){ \
      const int cb2 = 128 + (C) * 32 + 16 * gp + 4 * lhi; \
      const float4 gmA = *reinterpret_cast<const float4*>(&Pgs[cb2]); \
      const float4 c2A = *reinterpret_cast<const float4*>(&C2s[l][cb2]); \
      const float4 gmB = *reinterpret_cast<const float4*>(&Pgs[cb2 + 8]); \
      const float4 c2B = *reinterpret_cast<const float4*>(&C2s[l][cb2 + 8]); \
      us4 lo4, hi4; \
      lo4[0] = f2h(fast_gelu(fmaf((ACC)[8*gp+0], gmA.x, c2A.x))); \
      lo4[1] = f2h(fast_gelu(fmaf((ACC)[8*gp+1], gmA.y, c2A.y))); \
      lo4[2] = f2h(fast_gelu(fmaf((ACC)[8*gp+2], gmA.z, c2A.z))); \
      lo4[3] = f2h(fast_gelu(fmaf((ACC)[8*gp+3], gmA.w, c2A.w))); \
      hi4[0] = f2h(fast_gelu(fmaf((ACC)[8*gp+4], gmB.x, c2B.x))); \
      hi4[1] = f2h(fast_gelu(fmaf((ACC)[8*gp+5], gmB.y, c2B.y))); \
      hi4[2] = f2h(fast_gelu(fmaf((ACC)[8*gp+6], gmB.z, c2B.z))); \
      hi4[3] = f2h(fast_gelu(fmaf((ACC)[8*gp+7], gmB.w, c2B.w))); \
      *reinterpret_cast<us4*>(&T0[ACOL(arow, cb2)])     = lo4; \
      *reinterpret_cast<us4*>(&T0[ACOL(arow, cb2 + 8)]) = hi4; \
    } } while(0)

#pragma unroll
  for (int l = 0; l < 4; ++l){
    const unsigned short* Wl = WTh + l * 65536;

    // ---- pass A: col groups 0..3, K over full row ----
    ZERO16(acc0); ZERO16(acc1); ZERO16(acc2); ZERO16(acc3);
#pragma unroll
    for (int ks = 0; ks < 16; ++ks){
      f16x8 ah = LDW(&T0[ACOL(arow, ks * 16 + lhi * 8)]);
      STEP_A(0, acc0);
      STEP_A(1, acc1);
      STEP_A(2, acc2);
      STEP_A(3, acc3);
    }
    STASH(0, acc0); STASH(1, acc1); STASH(2, acc2); STASH(3, acc3);

    // ---- pass B: col groups 4..7, K over the (still intact) row ----
    ZERO16(acc0); ZERO16(acc1); ZERO16(acc2); ZERO16(acc3);
#pragma unroll
    for (int ks = 0; ks < 16; ++ks){
      f16x8 ah = LDW(&T0[ACOL(arow, ks * 16 + lhi * 8)]);
      STEP_B(0, acc0);
      STEP_B(1, acc1);
      STEP_B(2, acc2);
      STEP_B(3, acc3);
    }

    // ---- all reads of the row done: write stash (cols 0..127) ----
#pragma unroll
    for (int c = 0; c < 4; ++c){
#pragma unroll
      for (int gp = 0; gp < 2; ++gp){
        us8 v = __builtin_bit_cast(us8, st[c * 2 + gp]);
        us4 lo4, hi4;
        lo4[0]=v[0]; lo4[1]=v[1]; lo4[2]=v[2]; lo4[3]=v[3];
        hi4[0]=v[4]; hi4[1]=v[5]; hi4[2]=v[6]; hi4[3]=v[7];
        const int cb2 = c * 32 + 16 * gp + 4 * lhi;
        *reinterpret_cast<us4*>(&T0[ACOL(arow, cb2)])     = lo4;
        *reinterpret_cast<us4*>(&T0[ACOL(arow, cb2 + 8)]) = hi4;
      }
    }
    // ---- pass-B epilogue: FiLM+gelu, write cols 128..255 ----
    WRITE_B(0, acc0); WRITE_B(1, acc1); WRITE_B(2, acc2); WRITE_B(3, acc3);
    // no barrier: next layer reads only this wave's own rows
  }

  // ---------------- head (256 -> 3) + tanh: reads own rows, no barrier -----
#pragma unroll
  for (int s = 0; s < 2; ++s){
    f32x4 ao = (f32x4){0.0f, 0.0f, 0.0f, 0.0f};
#pragma unroll
    for (int ks = 0; ks < 8; ++ks){
      const int kc = ks * 32 + lg * 8;
      f16x8 va = LDW(&T0[ACOL(wv * 32 + s * 16 + l15, kc)]);
      f16x8 vb = LDW(&WoT[(ks * 64 + lane) * 8]);
      ao = __builtin_amdgcn_mfma_f32_16x16x32_f16(va, vb, ao, 0, 0, 0);
    }
    if (l15 < 3){
      const float bo = bout[l15];
#pragma unroll
      for (int rg2 = 0; rg2 < 4; ++rg2){
        const int row = wv * 32 + s * 16 + lg * 4 + rg2;
        out[((size_t)bi * 16384 + n0 + row) * 3 + l15] = fast_tanh(ao[rg2] + bo);
      }
    }
  }
}

// ------------------------------- launch --------------------------------------
extern "C" void kernel_launch(void* const* d_in, const int* in_sizes, int n_in,
                              void* d_out, int out_size, void* d_ws, size_t ws_size,
                              hipStream_t stream){
  (void)in_sizes; (void)n_in; (void)out_size;
  const float* fg     = (const float*)d_in[0];
  const float* cv     = (const float*)d_in[1];
  const float* coords = (const float*)d_in[2];
  const float* Wc     = (const float*)d_in[3];
  const float* bc     = (const float*)d_in[4];
  const float* W0     = (const float*)d_in[5];
  const float* b0     = (const float*)d_in[6];
  const float* W1     = (const float*)d_in[7];
  const float* b1     = (const float*)d_in[8];
  const float* W2     = (const float*)d_in[9];
  const float* b2     = (const float*)d_in[10];
  const float* W3     = (const float*)d_in[11];
  const float* b3     = (const float*)d_in[12];
  const float* Wout   = (const float*)d_in[13];
  const float* bout   = (const float*)d_in[14];

  char* ws = (char*)d_ws;
  float*          p1    = (float*)(ws);                    // 8*32*32*64 f32 = 2 MB
  float*          p2    = (float*)(ws + 2097152);          // 8*16*16*64 f32 = 512 KB
  unsigned short* WTh   = (unsigned short*)(ws + 2621440); // 4*256*256 f16 = 512 KB
  unsigned short* WoT   = (unsigned short*)(ws + 3670016); // 8*64*8 f16
  float*          gam   = (float*)(ws + 3678208);          // 8*256 f32
  float*          bet   = (float*)(ws + 3686400);          // 8*256 f32
  // PE table (optional, 1.5 MB)
  const size_t PEH_OFF = 4194304, PE_END = 5767168;
  bool use_pe = (ws_size >= PE_END);
  unsigned short* PEh = use_pe ? (unsigned short*)(ws + PEH_OFF) : nullptr;
  float* outp = (float*)d_out;

  pyr_kernel<<<dim3(2048), dim3(256), 0, stream>>>(fg, p1, 32, 32, 2.0f);
  pyr_kernel<<<dim3(512),  dim3(256), 0, stream>>>(fg, p2, 16, 16, 4.0f);
  prep_wt  <<<dim3(1024),  dim3(256), 0, stream>>>(W0, W1, W2, W3, WTh);
  prep_misc<<<dim3(32),    dim3(256), 0, stream>>>(cv, Wc, bc, Wout, gam, bet, WoT);
  if (use_pe)
    pe_kernel<<<dim3(768), dim3(256), 0, stream>>>(coords, PEh);
  dec_main <<<dim3(512),   dim3(512), 0, stream>>>(fg, coords, p1, p2, WTh, WoT,
                                                   PEh,
                                                   gam, bet, b0, b1, b2, b3, bout, outp);
}

// Round 25
// 188.515 us; speedup vs baseline: 1.9042x; 1.9042x over previous
//
#include <hip/hip_runtime.h>
#include <math.h>

typedef _Float16 f16x8 __attribute__((ext_vector_type(8)));
typedef float f32x4 __attribute__((ext_vector_type(4)));
typedef float f32x16 __attribute__((ext_vector_type(16)));
typedef unsigned short us8 __attribute__((ext_vector_type(8)));
typedef unsigned short us4 __attribute__((ext_vector_type(4)));

#define PI_F 3.14159265358979323846f

__device__ __forceinline__ unsigned short f2h(float f){
  _Float16 hi = (_Float16)f;
  return __builtin_bit_cast(unsigned short, hi);
}

__device__ __forceinline__ float fast_gelu(float v){
  float u2 = v * v;
  float z  = v * fmaf(u2, 0.03567740814f, 0.7978845608f);
  float e  = __builtin_amdgcn_exp2f(z * 2.885390082f);   // 2*log2(e)
  float r  = __builtin_amdgcn_rcpf(e + 1.0f);
  return v - v * r;
}

__device__ __forceinline__ float fast_tanh(float v){
  float e = __builtin_amdgcn_exp2f(v * 2.885390082f);
  float r = __builtin_amdgcn_rcpf(e + 1.0f);
  return 1.0f - 2.0f * r;
}

// LDS tile addressing in ushort units, XOR swizzle for bank balance
#define ACOL(rr,cc) (((rr) << 8) + ((cc) ^ ((((rr) & 15)) << 3)))

#define LDW(ptr) __builtin_bit_cast(f16x8, *reinterpret_cast<const us8*>(ptr))

// ---------------- pyramid (jax.image.resize bilinear, antialias=True) -------
__global__ void pyr_kernel(const float* __restrict__ fg, float* __restrict__ out,
                           int Ho, int Wo, float inv_scale){
  int idx = blockIdx.x * blockDim.x + threadIdx.x;
  int total = 8 * Ho * Wo * 64;
  if (idx >= total) return;
  int c  = idx & 63;
  int xy = idx >> 6;
  int x  = xy % Wo;
  int y  = (xy / Wo) % Ho;
  int b  = xy / (Wo * Ho);
  float cyc = inv_scale * (y + 0.5f) - 0.5f;
  float cxc = inv_scale * (x + 0.5f) - 0.5f;
  int iy0 = (int)ceilf(cyc - inv_scale); if (iy0 < 0) iy0 = 0;
  int iy1 = (int)floorf(cyc + inv_scale); if (iy1 > 63) iy1 = 63;
  int ix0 = (int)ceilf(cxc - inv_scale); if (ix0 < 0) ix0 = 0;
  int ix1 = (int)floorf(cxc + inv_scale); if (ix1 > 63) ix1 = 63;
  float rinv = 1.0f / inv_scale;
  float wxs = 0.0f;
  for (int ix = ix0; ix <= ix1; ++ix){
    float w = 1.0f - fabsf(ix - cxc) * rinv;
    if (w > 0.0f) wxs += w;
  }
  float wys = 0.0f, acc = 0.0f;
  for (int iy = iy0; iy <= iy1; ++iy){
    float wy = 1.0f - fabsf(iy - cyc) * rinv;
    if (wy <= 0.0f) continue;
    wys += wy;
    const float* rowp = fg + (((b * 64) + iy) * 64) * 64 + c;
    for (int ix = ix0; ix <= ix1; ++ix){
      float wx = 1.0f - fabsf(ix - cxc) * rinv;
      if (wx <= 0.0f) continue;
      acc += wy * wx * rowp[ix * 64];
    }
  }
  out[idx] = acc / (wys * wxs);
}

// ------------- posenc table: PE[n][48] f16 (shared across images) -----------
__global__ void pe_kernel(const float* __restrict__ coords,
                          unsigned short* __restrict__ peh){
  int idx = blockIdx.x * 256 + threadIdx.x;   // < 196608
  if (idx >= 16384 * 12) return;
  int n = idx / 12, slot = idx % 12;
  const float cy = coords[2 * n], cx = coords[2 * n + 1];
  if (slot == 0){
    peh[n * 48 + 0] = f2h(cy);
    peh[n * 48 + 1] = f2h(cx);
  } else if (slot <= 10){
    int i = slot - 1;
    float f = PI_F * (float)(1 << i);
    float sy, cyv, sx, cxv;
    sincosf(cy * f, &sy, &cyv);
    sincosf(cx * f, &sx, &cxv);
    peh[n * 48 + 2 + 4 * i] = f2h(sy);
    peh[n * 48 + 3 + 4 * i] = f2h(sx);
    peh[n * 48 + 4 + 4 * i] = f2h(cyv);
    peh[n * 48 + 5 + 4 * i] = f2h(cxv);
  } else {
#pragma unroll
    for (int j = 42; j < 48; ++j) peh[n * 48 + j] = 0;
  }
}

// ------------- weight prep: pre-tiled per-lane 32x32x16 MFMA fragments ------
// WT[l][cfg][ks][lane][e]: col = cfg*32 + (lane&31), k = ks*16 + (lane>>5)*8 + e
// layer0 k-remap: k<42 -> W0 row k; 42..47 pad; 48..239 -> row k-6; 240..255 pad
__global__ void prep_wt(const float* __restrict__ W0, const float* __restrict__ W1,
                        const float* __restrict__ W2, const float* __restrict__ W3,
                        unsigned short* __restrict__ WTh){
  int idx = blockIdx.x * 256 + threadIdx.x;      // < 262144
  int l    = idx >> 16;
  int rem  = idx & 65535;
  int cfg  = rem >> 13;          // 0..7
  int ks   = (rem >> 9) & 15;    // 0..15
  int lane = (rem >> 3) & 63;
  int e    = idx & 7;
  int col  = cfg * 32 + (lane & 31);
  int k    = ks * 16 + (lane >> 5) * 8 + e;
  float v;
  if (l == 0){
    int row; bool valid;
    if (k < 42)                 { row = k;     valid = true; }
    else if (k >= 48 && k < 240){ row = k - 6; valid = true; }
    else                        { row = 0;     valid = false; }
    v = valid ? W0[row * 256 + col] : 0.0f;
  } else {
    const float* W = (l == 1) ? W1 : ((l == 2) ? W2 : W3);
    v = W[k * 256 + col];
  }
  WTh[idx] = f2h(v);
}

// ------------- FiLM params + Wout tiled fragments (16x16 head) --------------
__global__ void prep_misc(const float* __restrict__ cv, const float* __restrict__ Wc,
                          const float* __restrict__ bc, const float* __restrict__ Wout,
                          float* __restrict__ gamma, float* __restrict__ beta,
                          unsigned short* __restrict__ WoT){
  int idx = blockIdx.x * 256 + threadIdx.x;      // < 8192
  if (idx < 4096){
    int b = idx >> 9, j = idx & 511;
    float a = bc[j];
    for (int c = 0; c < 64; ++c) a += cv[b * 64 + c] * Wc[c * 512 + j];
    if (j < 256) gamma[b * 256 + j] = a + 1.0f;
    else         beta[b * 256 + (j - 256)] = a;
  } else {
    int j = idx - 4096;                // WoT[ks][lane][e]
    int ks = j >> 9, lane = (j >> 3) & 63, e = j & 7;
    int col = lane & 15;
    int k = ks * 32 + (lane >> 4) * 8 + e;
    float v = (col < 3) ? Wout[k * 3 + col] : 0.0f;
    WoT[j] = f2h(v);
  }
}

// ------------------------------- main ---------------------------------------
// R18 (best validated: dec_main 159.5us, VGPR 104, zero spill): R17 structure
// with a depth-8 B-prefetch ring + cross-layer wraparound: slots consumed at
// iter ks are refilled with frag ks+8 (same layer) or, for ks>=8, with layer
// l+1's frag ks-8 — next layer's prologue loads are in flight across the
// epilogue+barrier so B-loads never stall the K-loop. All ring indices are
// compile-time (both loops fully unrolled).
__global__ __launch_bounds__(512, 2)
void dec_main(const float* __restrict__ fg, const float* __restrict__ coords,
              const float* __restrict__ p1, const float* __restrict__ p2,
              const unsigned short* __restrict__ WTh,
              const unsigned short* __restrict__ WoT,
              const unsigned short* __restrict__ peh,
              const float* __restrict__ gamma, const float* __restrict__ beta,
              const float* __restrict__ b0, const float* __restrict__ b1,
              const float* __restrict__ b2, const float* __restrict__ b3,
              const float* __restrict__ bout, float* __restrict__ out){
  __shared__ __align__(16) unsigned short Ah0[80 * 256];  // 40 KB T0 (rows 0..63 used)
  __shared__ __align__(16) unsigned short Ah1[80 * 256];  // 40 KB T1 (pad -> 1 blk/CU)
  __shared__ __align__(16) float Pgs[256];                // gamma
  __shared__ __align__(16) float C2s[4][256];             // bs*gm + bt per layer

  const int t  = threadIdx.x;
  const int bi = blockIdx.x >> 8;           // image 0..7   (R4-validated decode)
  const int n0 = (blockIdx.x & 255) * 64;   // first coord row of this block

  const int lane = t & 63;
  const int wv   = t >> 6;         // 0..7
  const int l15  = lane & 15;      // head (16x16) lane decode
  const int lg   = lane >> 4;
  const int l31  = lane & 31;      // 32x32 lane decode
  const int lhi  = lane >> 5;      // 0/1

  const int rg   = wv >> 2;        // row group 0/1  -> rows rg*32..+32
  const int cg   = wv & 3;         // col group 0..3 -> cols cg*64..+64
  const int arow = rg * 32 + l31;  // this lane's A row

  // B fragment offsets (cfg = cg*2 + {0,1})
  const int b0off = (cg * 2)     * 8192 + lane * 8;
  const int b1off = (cg * 2 + 1) * 8192 + lane * 8;

  // ---------------- phase 0: params + features into T0 ---------------------
  if (t < 256){
    // FiLM param staging: Pgs = gamma, C2s[l] = b_l*gm + bt
    const float gm = gamma[bi * 256 + t];
    const float bt = beta[bi * 256 + t];
    Pgs[t] = gm;
    C2s[0][t] = fmaf(b0[t], gm, bt);
    C2s[1][t] = fmaf(b1[t], gm, bt);
    C2s[2][t] = fmaf(b2[t], gm, bt);
    C2s[3][t] = fmaf(b3[t], gm, bt);

    const int r = t >> 2, q = t & 3;
    const int n = n0 + r;
    const float cy = coords[2 * n], cx = coords[2 * n + 1];

    if (q == 0){
      if (peh){
        const unsigned short* ph = peh + (size_t)n * 48;
#pragma unroll
        for (int u = 0; u < 6; ++u){
          us8 vh = *reinterpret_cast<const us8*>(ph + u * 8);
          *reinterpret_cast<us8*>(&Ah0[ACOL(r, u * 8)]) = vh;
        }
      } else {
        float e[48];
        e[0] = cy; e[1] = cx;
#pragma unroll
        for (int i = 0; i < 10; ++i){
          float f = PI_F * (float)(1 << i);
          float sy, cyv, sx, cxv;
          sincosf(cy * f, &sy, &cyv);
          sincosf(cx * f, &sx, &cxv);
          e[2 + 4 * i] = sy;
          e[3 + 4 * i] = sx;
          e[4 + 4 * i] = cyv;
          e[5 + 4 * i] = cxv;
        }
#pragma unroll
        for (int j = 42; j < 48; ++j) e[j] = 0.0f;
#pragma unroll
        for (int u = 0; u < 6; ++u){
          us8 vh;
#pragma unroll
          for (int j = 0; j < 8; ++j) vh[j] = f2h(e[8 * u + j]);
          *reinterpret_cast<us8*>(&Ah0[ACOL(r, u * 8)]) = vh;
        }
      }
    }
    if (q == 1){   // zero pad cols 240..255
      us8 z = {0,0,0,0,0,0,0,0};
      *reinterpret_cast<us8*>(&Ah0[ACOL(r, 240)]) = z;
      *reinterpret_cast<us8*>(&Ah0[ACOL(r, 248)]) = z;
    }

    // bilinear sample 16 channels per thread from each pyramid level
#pragma unroll
    for (int L = 0; L < 3; ++L){
      const int HL = 64 >> L;
      const float* g = (L == 0) ? fg : ((L == 1) ? p1 : p2);
      float yy = (cy + 1.0f) * 0.5f * (HL - 1);
      float xx = (cx + 1.0f) * 0.5f * (HL - 1);
      float y0f = floorf(yy), x0f = floorf(xx);
      float wy = yy - y0f, wx = xx - x0f;
      int y0 = (int)y0f, x0 = (int)x0f;
      y0 = min(max(y0, 0), HL - 1); x0 = min(max(x0, 0), HL - 1);
      int y1 = min(y0 + 1, HL - 1), x1 = min(x0 + 1, HL - 1);
      const int c0 = q * 16;
      const float* g00 = g + (((bi * HL + y0) * HL) + x0) * 64 + c0;
      const float* g01 = g + (((bi * HL + y0) * HL) + x1) * 64 + c0;
      const float* g10 = g + (((bi * HL + y1) * HL) + x0) * 64 + c0;
      const float* g11 = g + (((bi * HL + y1) * HL) + x1) * 64 + c0;
      float w00 = (1 - wy) * (1 - wx), w01 = (1 - wy) * wx;
      float w10 = wy * (1 - wx),       w11 = wy * wx;
      float o[16];
#pragma unroll
      for (int u = 0; u < 4; ++u){
        float4 v0 = *reinterpret_cast<const float4*>(g00 + 4 * u);
        float4 v1 = *reinterpret_cast<const float4*>(g01 + 4 * u);
        float4 v2 = *reinterpret_cast<const float4*>(g10 + 4 * u);
        float4 v3 = *reinterpret_cast<const float4*>(g11 + 4 * u);
        o[4*u+0] = w00*v0.x + w01*v1.x + w10*v2.x + w11*v3.x;
        o[4*u+1] = w00*v0.y + w01*v1.y + w10*v2.y + w11*v3.y;
        o[4*u+2] = w00*v0.z + w01*v1.z + w10*v2.z + w11*v3.z;
        o[4*u+3] = w00*v0.w + w01*v1.w + w10*v2.w + w11*v3.w;
      }
      us8 h0, h1;
#pragma unroll
      for (int j = 0; j < 8; ++j){
        h0[j] = f2h(o[j]);
        h1[j] = f2h(o[8 + j]);
      }
      const int colb = 48 + 64 * L + 16 * q;
      *reinterpret_cast<us8*>(&Ah0[ACOL(r, colb)])     = h0;
      *reinterpret_cast<us8*>(&Ah0[ACOL(r, colb + 8)]) = h1;
    }
  }

  // B-prefetch ring: layer-0 fragments 0..7 issued BEFORE the barrier
  f16x8 bf0[8], bf1[8];
#pragma unroll
  for (int p = 0; p < 8; ++p){
    bf0[p] = LDW(WTh + b0off + p * 512);
    bf1[p] = LDW(WTh + b1off + p * 512);
  }
  __syncthreads();

  // ---------------- phase 1: 4 FiLM-gelu MLP layers (32x32x16, swapped) ----
  // Double-buffered tiles: layer l reads T[l&1], writes T[1^(l&1)]; ONE barrier.
#pragma unroll
  for (int l = 0; l < 4; ++l){
    const unsigned short* Rh   = (l & 1) ? Ah1 : Ah0;   // read tile
    unsigned short*       Wh_t = (l & 1) ? Ah0 : Ah1;   // write tile
    const unsigned short* Wcur = WTh + l * 65536;
    const unsigned short* Wnxt = WTh + (l + 1) * 65536; // only used when l<3

    f32x16 accA, accB;
#pragma unroll
    for (int j = 0; j < 16; ++j){ accA[j] = 0.0f; accB[j] = 0.0f; }

#pragma unroll
    for (int ks = 0; ks < 16; ++ks){
      const int cur = ks & 7;                 // compile-time (full unroll)
      const int kc = ks * 16 + lhi * 8;
      f16x8 ah  = LDW(&Rh[ACOL(arow, kc)]);
      f16x8 b0v = bf0[cur], b1v = bf1[cur];
      // ring refill: same-layer frag ks+8, or next layer's frag ks-8
      if (ks < 8){
        bf0[cur] = LDW(Wcur + b0off + (ks + 8) * 512);
        bf1[cur] = LDW(Wcur + b1off + (ks + 8) * 512);
      } else if (l < 3){
        bf0[cur] = LDW(Wnxt + b0off + (ks - 8) * 512);
        bf1[cur] = LDW(Wnxt + b1off + (ks - 8) * 512);
      }
      // SWAPPED operands: weights first (D reg = weight col),
      // activations second (D lane = activation row)
      accA = __builtin_amdgcn_mfma_f32_32x32x16_f16(b0v, ah, accA, 0, 0, 0);
      accB = __builtin_amdgcn_mfma_f32_32x32x16_f16(b1v, ah, accB, 0, 0, 0);
    }
    // no barrier here: epilogue writes the OTHER tile (disjoint).

    // epilogue: reg-quad g covers cols colb..colb+3 at row arow
#define EPI32(ACC, CF) do { \
      _Pragma("unroll") \
      for (int g = 0; g < 4; ++g){ \
        const int colb = cg * 64 + (CF) * 32 + 4 * lhi + 8 * g; \
        const float4 gm4 = *reinterpret_cast<const float4*>(&Pgs[colb]); \
        const float4 c24 = *reinterpret_cast<const float4*>(&C2s[l][colb]); \
        us4 hh; \
        { float v = fmaf((ACC)[4*g+0], gm4.x, c24.x); hh[0] = f2h(fast_gelu(v)); } \
        { float v = fmaf((ACC)[4*g+1], gm4.y, c24.y); hh[1] = f2h(fast_gelu(v)); } \
        { float v = fmaf((ACC)[4*g+2], gm4.z, c24.z); hh[2] = f2h(fast_gelu(v)); } \
        { float v = fmaf((ACC)[4*g+3], gm4.w, c24.w); hh[3] = f2h(fast_gelu(v)); } \
        *reinterpret_cast<us4*>(&Wh_t[ACOL(arow, colb)]) = hh; \
      } } while(0)
    EPI32(accA, 0);
    EPI32(accB, 1);
#undef EPI32
    __syncthreads();   // writes to T[next] visible before next layer reads it
  }

  // ---------------- phase 2: output head (256 -> 3) + tanh (16x16 path) ----
  // Final activations in T0 (l=3 wrote T0).
  if (wv < 4){
    f32x4 ao = (f32x4){0.0f, 0.0f, 0.0f, 0.0f};
#pragma unroll
    for (int ks = 0; ks < 8; ++ks){
      const int kc = ks * 32 + lg * 8;
      f16x8 va = LDW(&Ah0[ACOL(wv * 16 + l15, kc)]);
      f16x8 vb = LDW(&WoT[(ks * 64 + lane) * 8]);
      ao = __builtin_amdgcn_mfma_f32_16x16x32_f16(va, vb, ao, 0, 0, 0);
    }
    if (l15 < 3){
      const float bo = bout[l15];
#pragma unroll
      for (int rg2 = 0; rg2 < 4; ++rg2){
        const int row = wv * 16 + lg * 4 + rg2;
        out[((size_t)bi * 16384 + n0 + row) * 3 + l15] = fast_tanh(ao[rg2] + bo);
      }
    }
  }
}

// ------------------------------- launch --------------------------------------
extern "C" void kernel_launch(void* const* d_in, const int* in_sizes, int n_in,
                              void* d_out, int out_size, void* d_ws, size_t ws_size,
                              hipStream_t stream){
  (void)in_sizes; (void)n_in; (void)out_size;
  const float* fg     = (const float*)d_in[0];
  const float* cv     = (const float*)d_in[1];
  const float* coords = (const float*)d_in[2];
  const float* Wc     = (const float*)d_in[3];
  const float* bc     = (const float*)d_in[4];
  const float* W0     = (const float*)d_in[5];
  const float* b0     = (const float*)d_in[6];
  const float* W1     = (const float*)d_in[7];
  const float* b1     = (const float*)d_in[8];
  const float* W2     = (const float*)d_in[9];
  const float* b2     = (const float*)d_in[10];
  const float* W3     = (const float*)d_in[11];
  const float* b3     = (const float*)d_in[12];
  const float* Wout   = (const float*)d_in[13];
  const float* bout   = (const float*)d_in[14];

  char* ws = (char*)d_ws;
  float*          p1    = (float*)(ws);                    // 8*32*32*64 f32 = 2 MB
  float*          p2    = (float*)(ws + 2097152);          // 8*16*16*64 f32 = 512 KB
  unsigned short* WTh   = (unsigned short*)(ws + 2621440); // 4*256*256 f16 = 512 KB
  unsigned short* WoT   = (unsigned short*)(ws + 3670016); // 8*64*8 f16
  float*          gam   = (float*)(ws + 3678208);          // 8*256 f32
  float*          bet   = (float*)(ws + 3686400);          // 8*256 f32
  // PE table (optional, 1.5 MB)
  const size_t PEH_OFF = 4194304, PE_END = 5767168;
  bool use_pe = (ws_size >= PE_END);
  unsigned short* PEh = use_pe ? (unsigned short*)(ws + PEH_OFF) : nullptr;
  float* outp = (float*)d_out;

  pyr_kernel<<<dim3(2048), dim3(256), 0, stream>>>(fg, p1, 32, 32, 2.0f);
  pyr_kernel<<<dim3(512),  dim3(256), 0, stream>>>(fg, p2, 16, 16, 4.0f);
  prep_wt  <<<dim3(1024),  dim3(256), 0, stream>>>(W0, W1, W2, W3, WTh);
  prep_misc<<<dim3(32),    dim3(256), 0, stream>>>(cv, Wc, bc, Wout, gam, bet, WoT);
  if (use_pe)
    pe_kernel<<<dim3(768), dim3(256), 0, stream>>>(coords, PEh);
  dec_main <<<dim3(2048),  dim3(512), 0, stream>>>(fg, coords, p1, p2, WTh, WoT,
                                                   PEh,
                                                   gam, bet, b0, b1, b2, b3, bout, outp);
}